// Round 3
// baseline (1086.573 us; speedup 1.0000x reference)
//
#include <hip/hip_runtime.h>
#include <hip/hip_bf16.h>

#define NND 100000
#define NED 1200000
#define NHOP 3
#define DM 64
#define EPSV 1e-5f
#define NB1 391   // ceil(NND/256)

typedef long long i64;
typedef unsigned short u16;
typedef unsigned int u32;

__device__ __forceinline__ float rlf(float v, int k) {
    return __builtin_bit_cast(float, __builtin_amdgcn_readlane(__builtin_bit_cast(int, v), k));
}
__device__ __forceinline__ float bf2f(u16 b) {
    return __builtin_bit_cast(float, (u32)b << 16);
}
__device__ __forceinline__ u16 f2bf(float f) {
    u32 u = __builtin_bit_cast(u32, f);
    return (u16)((u + 0x7FFFu + ((u >> 16) & 1u)) >> 16);
}

// --- softmax of comb_w rows: [4][3] -> wsoft ---
__global__ void k_weights(const float* __restrict__ comb_w, float* __restrict__ wsoft) {
    int j = threadIdx.x;
    if (j < NHOP + 1) {
        float a0 = comb_w[j * 3 + 0], a1 = comb_w[j * 3 + 1], a2 = comb_w[j * 3 + 2];
        float mx = fmaxf(a0, fmaxf(a1, a2));
        float e0 = expf(a0 - mx), e1 = expf(a1 - mx), e2 = expf(a2 - mx);
        float s = 1.0f / (e0 + e1 + e2);
        wsoft[j * 3 + 0] = e0 * s; wsoft[j * 3 + 1] = e1 * s; wsoft[j * 3 + 2] = e2 * s;
    }
}

// --- xw = (sum_i w[j,i]*bb[1+i]) @ W -> bf16; optional dinv row-scale; optional BN-stats ---
__global__ __launch_bounds__(256) void k_gemm(const float* __restrict__ bb,
                                              const float* __restrict__ wsoft, int j,
                                              const float* __restrict__ W,
                                              const float* __restrict__ dinv, int scale,
                                              float* __restrict__ stats, int dostats,
                                              u16* __restrict__ xw) {
    const int lane = threadIdx.x & 63;
    float Wcol[DM];
#pragma unroll
    for (int k = 0; k < DM; k++) Wcol[k] = W[k * DM + lane];
    const float w0 = wsoft[j * 3 + 0], w1 = wsoft[j * 3 + 1], w2 = wsoft[j * 3 + 2];
    const float* b1 = bb + (i64)1 * NND * DM;
    const float* b2 = bb + (i64)2 * NND * DM;
    const float* b3 = bb + (i64)3 * NND * DM;
    int wave = (int)((blockIdx.x * blockDim.x + threadIdx.x) >> 6);
    int nw = (int)((gridDim.x * blockDim.x) >> 6);
    float s = 0.f, sq = 0.f;
    for (int n = wave; n < NND; n += nw) {
        i64 base = (i64)n * DM + lane;
        float m = w0 * b1[base] + w1 * b2[base] + w2 * b3[base];
        float a0 = 0.f, a1 = 0.f, a2 = 0.f, a3 = 0.f;
#pragma unroll
        for (int k = 0; k < DM; k += 4) {
            a0 = fmaf(rlf(m, k + 0), Wcol[k + 0], a0);
            a1 = fmaf(rlf(m, k + 1), Wcol[k + 1], a1);
            a2 = fmaf(rlf(m, k + 2), Wcol[k + 2], a2);
            a3 = fmaf(rlf(m, k + 3), Wcol[k + 3], a3);
        }
        float r = (a0 + a1) + (a2 + a3);
        if (scale) r *= dinv[n];
        xw[base] = f2bf(r);
        s += r; sq += r * r;
    }
    if (dostats) {
        __shared__ float ls[4][DM], lq[4][DM];
        int row = threadIdx.x >> 6;
        ls[row][lane] = s; lq[row][lane] = sq;
        __syncthreads();
        if (row == 0) {
            s  = ls[0][lane] + ls[1][lane] + ls[2][lane] + ls[3][lane];
            sq = lq[0][lane] + lq[1][lane] + lq[2][lane] + lq[3][lane];
            unsafeAtomicAdd(&stats[lane], s);
            unsafeAtomicAdd(&stats[DM + lane], sq);
        }
    }
}

// --- integer in-degree histogram ---
__global__ __launch_bounds__(256) void k_deg(const int* __restrict__ dst, int* __restrict__ deg) {
    int i = blockIdx.x * blockDim.x + threadIdx.x;
    int stride = gridDim.x * blockDim.x;
    for (int e = i; e < NED; e += stride) atomicAdd(&deg[dst[e]], 1);
}

// --- scan level 1: per-block exclusive scan of deg; block totals; dinv ---
__global__ __launch_bounds__(256) void k_scan1(const int* __restrict__ deg,
                                               int* __restrict__ off,
                                               int* __restrict__ partials,
                                               float* __restrict__ dinv) {
    int t = threadIdx.x;
    int n = blockIdx.x * 256 + t;
    int d = (n < NND) ? deg[n] : 0;
    if (n < NND) dinv[n] = rsqrtf((float)d + 1.0f);
    __shared__ int sh[256];
    sh[t] = d;
    __syncthreads();
    for (int o = 1; o < 256; o <<= 1) {
        int v = (t >= o) ? sh[t - o] : 0;
        __syncthreads();
        sh[t] += v;
        __syncthreads();
    }
    if (n < NND) off[n] = sh[t] - d;       // block-local exclusive
    if (t == 255) partials[blockIdx.x] = sh[255];
}

// --- scan level 2: exclusive scan of 391 block totals ---
__global__ __launch_bounds__(512) void k_scan2(int* __restrict__ partials) {
    int t = threadIdx.x;
    int d = (t < NB1) ? partials[t] : 0;
    __shared__ int sh[512];
    sh[t] = d;
    __syncthreads();
    for (int o = 1; o < 512; o <<= 1) {
        int v = (t >= o) ? sh[t - o] : 0;
        __syncthreads();
        sh[t] += v;
        __syncthreads();
    }
    if (t < NB1) partials[t] = sh[t] - d;  // exclusive block base
}

// --- bucket: sortedsrc grouped by dst; off doubles as cursor (becomes local_excl+cnt) ---
__global__ __launch_bounds__(256) void k_bucket(const int* __restrict__ src,
                                                const int* __restrict__ dst,
                                                int* __restrict__ off,
                                                const int* __restrict__ partials,
                                                int* __restrict__ sortedsrc) {
    int i = blockIdx.x * blockDim.x + threadIdx.x;
    int stride = gridDim.x * blockDim.x;
    for (int e = i; e < NED; e += stride) {
        int d = dst[e];
        int pos = partials[d >> 8] + atomicAdd(&off[d], 1);
        sortedsrc[pos] = src[e];
    }
}

// --- gather: x[n] = (sum_{s in N(n)} xws[s] + xws[n]) * dinv[n]; 4-way ILP; fused stats ---
__global__ __launch_bounds__(256) void k_gather(const u16* __restrict__ xws,
                                                const int* __restrict__ sortedsrc,
                                                const int* __restrict__ off,
                                                const int* __restrict__ partials,
                                                const int* __restrict__ deg,
                                                const float* __restrict__ dinv,
                                                float* __restrict__ xbuf,
                                                float* __restrict__ stats) {
    const int lane = threadIdx.x & 63;
    int wave = (int)((blockIdx.x * blockDim.x + threadIdx.x) >> 6);
    int nw = (int)((gridDim.x * blockDim.x) >> 6);
    float s = 0.f, sq = 0.f;
    for (int n = wave; n < NND; n += nw) {
        int cnt = deg[n];
        int start = partials[n >> 8] + off[n] - cnt;   // off[n] = local_excl + cnt after bucket
        float acc = bf2f(xws[(i64)n * DM + lane]);     // self-loop (pre-scaled)
        int i = 0;
        while (i < cnt) {
            int m = cnt - i; if (m > 64) m = 64;
            int sl = (lane < m) ? sortedsrc[start + i + lane] : 0;
            int t = 0;
            for (; t + 4 <= m; t += 4) {
                int s0 = __builtin_amdgcn_readlane(sl, t + 0);
                int s1 = __builtin_amdgcn_readlane(sl, t + 1);
                int s2 = __builtin_amdgcn_readlane(sl, t + 2);
                int s3 = __builtin_amdgcn_readlane(sl, t + 3);
                float v0 = bf2f(xws[(i64)s0 * DM + lane]);
                float v1 = bf2f(xws[(i64)s1 * DM + lane]);
                float v2 = bf2f(xws[(i64)s2 * DM + lane]);
                float v3 = bf2f(xws[(i64)s3 * DM + lane]);
                acc += ((v0 + v1) + (v2 + v3));
            }
            for (; t < m; t++) {
                int ss = __builtin_amdgcn_readlane(sl, t);
                acc += bf2f(xws[(i64)ss * DM + lane]);
            }
            i += m;
        }
        float x = acc * dinv[n];
        xbuf[(i64)n * DM + lane] = x;
        s += x; sq += x * x;
    }
    __shared__ float ls[4][DM], lq[4][DM];
    int row = threadIdx.x >> 6;
    ls[row][lane] = s; lq[row][lane] = sq;
    __syncthreads();
    if (row == 0) {
        s  = ls[0][lane] + ls[1][lane] + ls[2][lane] + ls[3][lane];
        sq = lq[0][lane] + lq[1][lane] + lq[2][lane] + lq[3][lane];
        unsafeAtomicAdd(&stats[lane], s);
        unsafeAtomicAdd(&stats[DM + lane], sq);
    }
}

// --- BN apply + accumulate; mode 0 also folds ego BN; mode 2 adds log_softmax ---
// mode 0 (hop0): hidden  = BN_a(xwsA) + relu(BN_b(xbuf))
// mode 1 (hop1): hidden += relu(BN_b(xbuf))
// mode 2 (hop2): h = hidden + relu(BN_b(xbuf)); out = log_softmax(h)
__global__ __launch_bounds__(256) void k_apply(const float* __restrict__ xbuf,
                                               const u16* __restrict__ xwsA, int mode,
                                               const float* __restrict__ statsA,
                                               const float* __restrict__ statsB,
                                               float* __restrict__ hidden,
                                               float* __restrict__ out) {
    const int lane = threadIdx.x & 63;
    float meanB = statsB[lane] * (1.0f / NND);
    float varB = statsB[DM + lane] * (1.0f / NND) - meanB * meanB;
    float invB = rsqrtf(varB + EPSV);
    float meanA = 0.f, invA = 0.f;
    if (mode == 0) {
        meanA = statsA[lane] * (1.0f / NND);
        float varA = statsA[DM + lane] * (1.0f / NND) - meanA * meanA;
        invA = rsqrtf(varA + EPSV);
    }
    int wave = (int)((blockIdx.x * blockDim.x + threadIdx.x) >> 6);
    int nw = (int)((gridDim.x * blockDim.x) >> 6);
    for (int n = wave; n < NND; n += nw) {
        i64 i = (i64)n * DM + lane;
        float bn = (xbuf[i] - meanB) * invB;
        float r = fmaxf(bn, 0.0f);
        if (mode == 0) {
            hidden[i] = (bf2f(xwsA[i]) - meanA) * invA + r;
        } else if (mode == 1) {
            hidden[i] += r;
        } else {
            float h = hidden[i] + r;
            float mx = h;
#pragma unroll
            for (int o = 32; o >= 1; o >>= 1) mx = fmaxf(mx, __shfl_xor(mx, o));
            float e = expf(h - mx);
            float ssum = e;
#pragma unroll
            for (int o = 32; o >= 1; o >>= 1) ssum += __shfl_xor(ssum, o);
            out[i] = h - mx - logf(ssum);
        }
    }
}

extern "C" void kernel_launch(void* const* d_in, const int* in_sizes, int n_in,
                              void* d_out, int out_size, void* d_ws, size_t ws_size,
                              hipStream_t stream) {
    const float* bb     = (const float*)d_in[0];
    const float* comb_w = (const float*)d_in[1];
    const float* ego_W  = (const float*)d_in[2];
    const float* conv_W = (const float*)d_in[4];
    const int*   edges  = (const int*)d_in[6];
    float* out = (float*)d_out;

    const i64 NF = (i64)NND * DM;
    char* ws = (char*)d_ws;
    float* wsoft     = (float*)ws;                  // 64 f
    float* stats     = wsoft + 64;                  // 4*128 f
    u16*   xwsA      = (u16*)(stats + 512);         // NF bf16 (ego)
    u16*   xwsB      = xwsA + NF;                   // NF bf16 (per-hop)
    float* xbuf      = (float*)(xwsB + NF);         // NF f32
    float* dinv      = xbuf + NF;                   // NND f
    int*   deg       = (int*)(dinv + NND);          // NND i
    int*   off       = deg + NND;                   // NND i
    int*   partials  = off + NND;                   // 512 i
    int*   sortedsrc = partials + 512;              // NED i
    float* hidden = out;                            // alias d_out as accumulator

    k_weights<<<1, 64, 0, stream>>>(comb_w, wsoft);
    hipMemsetAsync(stats, 0, 4 * 128 * sizeof(float), stream);

    // ego: xwsA = multi0 @ ego_W (bf16, stats slot 0 fused)
    k_gemm<<<1024, 256, 0, stream>>>(bb, wsoft, 0, ego_W, dinv, 0, stats, 1, xwsA);

    for (int k = 0; k < NHOP; k++) {
        const int* src = edges + (i64)k * 2 * NED;
        const int* dst = src + NED;
        float* statsB = stats + (k + 1) * 128;
        hipMemsetAsync(deg, 0, NND * sizeof(int), stream);
        k_deg<<<1024, 256, 0, stream>>>(dst, deg);
        k_scan1<<<NB1, 256, 0, stream>>>(deg, off, partials, dinv);
        k_scan2<<<1, 512, 0, stream>>>(partials);
        k_gemm<<<1024, 256, 0, stream>>>(bb, wsoft, k + 1, conv_W + (i64)k * DM * DM,
                                         dinv, 1, statsB, 0, xwsB);
        k_bucket<<<1024, 256, 0, stream>>>(src, dst, off, partials, sortedsrc);
        k_gather<<<4096, 256, 0, stream>>>(xwsB, sortedsrc, off, partials, deg, dinv,
                                           xbuf, statsB);
        k_apply<<<512, 256, 0, stream>>>(xbuf, xwsA, k, stats, statsB, hidden, out);
    }
}